// Round 3
// baseline (1066.675 us; speedup 1.0000x reference)
//
#include <hip/hip_runtime.h>
#include <stdint.h>

#define T_TOKENS 8192
#define DDIM 1024
#define FDIM 3584
#define NEXP 8

#define MAXT1 72    // 256-row tiles: 16384/256 + 8
#define MAXT2 136   // 128-row tiles: 16384/128 + 8

typedef _Float16 f16x8 __attribute__((ext_vector_type(8)));
typedef float f32x4 __attribute__((ext_vector_type(4)));

__device__ __forceinline__ void gload16(const void* g, void* l) {
  __builtin_amdgcn_global_load_lds(
      (const __attribute__((address_space(1))) void*)g,
      (__attribute__((address_space(3))) void*)l, 16, 0, 0);
}

#define FENCE asm volatile("" ::: "memory")
#define BARRIER do { FENCE; __builtin_amdgcn_s_barrier(); FENCE; } while (0)

// One compute phase: read A-quad q (2 m-frags x 2 kk), optional extra work
// (B preload or staging) in the same window, then barrier -> setprio(1) ->
// 16 MFMA -> setprio(0) -> barrier. Uses LA/wm/l15/pc0/pc1/bf/acc from scope.
#define GPHASE(q, ...) {                                                                                     \
    f16x8 a0  = *(const f16x8*)&LA[(wm + ((q) * 2)     * 16 + l15) * 64 + pc0];                              \
    f16x8 a0k = *(const f16x8*)&LA[(wm + ((q) * 2)     * 16 + l15) * 64 + pc1];                              \
    f16x8 a1  = *(const f16x8*)&LA[(wm + ((q) * 2 + 1) * 16 + l15) * 64 + pc0];                              \
    f16x8 a1k = *(const f16x8*)&LA[(wm + ((q) * 2 + 1) * 16 + l15) * 64 + pc1];                              \
    __VA_ARGS__;                                                                                             \
    BARRIER;                                                                                                 \
    __builtin_amdgcn_s_setprio(1);                                                                           \
    _Pragma("unroll")                                                                                        \
    for (int j = 0; j < 4; j++) {                                                                            \
      acc[(q) * 2][j]     = __builtin_amdgcn_mfma_f32_16x16x32_f16(a0,  bf[0][j], acc[(q) * 2][j], 0, 0, 0); \
      acc[(q) * 2 + 1][j] = __builtin_amdgcn_mfma_f32_16x16x32_f16(a1,  bf[0][j], acc[(q) * 2 + 1][j], 0, 0, 0); \
    }                                                                                                        \
    _Pragma("unroll")                                                                                        \
    for (int j = 0; j < 4; j++) {                                                                            \
      acc[(q) * 2][j]     = __builtin_amdgcn_mfma_f32_16x16x32_f16(a0k, bf[1][j], acc[(q) * 2][j], 0, 0, 0); \
      acc[(q) * 2 + 1][j] = __builtin_amdgcn_mfma_f32_16x16x32_f16(a1k, bf[1][j], acc[(q) * 2 + 1][j], 0, 0, 0); \
    }                                                                                                        \
    __builtin_amdgcn_s_setprio(0);                                                                           \
    BARRIER;                                                                                                 \
  }

// ---------------- router: logits, softmax, top-2, expert lists; also emits xh=f16(x) ----
__global__ __launch_bounds__(256) void router_kernel(
    const float* __restrict__ x, const float* __restrict__ gw,
    float* __restrict__ logits_out, int* __restrict__ counts,
    int* __restrict__ tok_idx, float* __restrict__ tok_w,
    int2* __restrict__ tok_ref, _Float16* __restrict__ xh) {
  int t = blockIdx.x * 4 + (threadIdx.x >> 6);  // one wave per token
  int lane = threadIdx.x & 63;
  const float* xr = x + (size_t)t * DDIM;
  float acc[NEXP];
#pragma unroll
  for (int e = 0; e < NEXP; e++) acc[e] = 0.f;
  for (int c = 0; c < DDIM / 64; c++) {
    float xv = xr[c * 64 + lane];
    xh[(size_t)t * DDIM + c * 64 + lane] = (_Float16)xv;
#pragma unroll
    for (int e = 0; e < NEXP; e++) acc[e] += xv * gw[e * DDIM + c * 64 + lane];
  }
#pragma unroll
  for (int e = 0; e < NEXP; e++) {
    for (int off = 32; off > 0; off >>= 1) acc[e] += __shfl_xor(acc[e], off, 64);
  }
  if (lane == 0) {
    float m = acc[0];
    for (int e = 1; e < NEXP; e++) m = fmaxf(m, acc[e]);
    float p[NEXP];
    for (int e = 0; e < NEXP; e++) p[e] = expf(acc[e] - m);
    int e1 = 0;
    for (int e = 1; e < NEXP; e++) if (p[e] > p[e1]) e1 = e;  // strict > : lowest idx on tie
    int e2 = (e1 == 0) ? 1 : 0;
    for (int e = 0; e < NEXP; e++) { if (e == e1) continue; if (p[e] > p[e2]) e2 = e; }
    float wsum = p[e1] + p[e2];
    float w1v = p[e1] / wsum, w2v = p[e2] / wsum;
    for (int e = 0; e < NEXP; e++) logits_out[(size_t)t * NEXP + e] = acc[e];
    int pos1 = atomicAdd(&counts[e1], 1);
    tok_idx[e1 * T_TOKENS + pos1] = t; tok_w[e1 * T_TOKENS + pos1] = w1v;
    int pos2 = atomicAdd(&counts[e2], 1);
    tok_idx[e2 * T_TOKENS + pos2] = t; tok_w[e2 * T_TOKENS + pos2] = w2v;
    tok_ref[t] = make_int2((e1 << 13) | pos1, (e2 << 13) | pos2);
  }
}

// ---------------- prefix + compact tile schedules (256-row for gemm1, 128-row for gemm2) ----
__global__ void prefix_kernel(const int* __restrict__ counts, int* __restrict__ offsets,
                              int* __restrict__ sched1, int* __restrict__ sched2) {
  if (threadIdx.x == 0) {
    int s = 0, n1 = 0, n2 = 0;
    for (int e = 0; e < NEXP; e++) {
      offsets[e] = s;
      int cc = counts[e];
      int nt1 = (cc + 255) / 256;
      for (int i = 0; i < nt1; i++) sched1[n1++] = (e << 16) | i;
      int nt2 = (cc + 127) / 128;
      for (int i = 0; i < nt2; i++) sched2[n2++] = (e << 16) | i;
      s += cc;
    }
    offsets[NEXP] = s;
    for (; n1 < MAXT1; n1++) sched1[n1] = -1;
    for (; n2 < MAXT2; n2++) sched2[n2] = -1;
  }
}

// ---------------- transpose+convert: in[e][R][C] fp32 -> out[e][C][R] f16 ----------------
__global__ __launch_bounds__(256) void transpose_f16_kernel(
    const float* __restrict__ in, _Float16* __restrict__ out, int R, int C) {
  __shared__ _Float16 lt[64][72];
  size_t esz = (size_t)R * C;
  in += (size_t)blockIdx.z * esz;
  out += (size_t)blockIdx.z * esz;
  int r0 = blockIdx.y * 64, c0 = blockIdx.x * 64;
  int t = threadIdx.x;
  int r = t & 63, q = t >> 6;
  const float* src = in + (size_t)(r0 + r) * C + c0 + q * 16;
  float4 v0 = ((const float4*)src)[0];
  float4 v1 = ((const float4*)src)[1];
  float4 v2 = ((const float4*)src)[2];
  float4 v3 = ((const float4*)src)[3];
  _Float16 f[16] = {
      (_Float16)v0.x, (_Float16)v0.y, (_Float16)v0.z, (_Float16)v0.w,
      (_Float16)v1.x, (_Float16)v1.y, (_Float16)v1.z, (_Float16)v1.w,
      (_Float16)v2.x, (_Float16)v2.y, (_Float16)v2.z, (_Float16)v2.w,
      (_Float16)v3.x, (_Float16)v3.y, (_Float16)v3.z, (_Float16)v3.w};
#pragma unroll
  for (int j = 0; j < 16; j++) lt[q * 16 + j][r] = f[j];
  __syncthreads();
  _Float16* dst = out + (size_t)(c0 + r) * R + r0 + q * 16;
  *(f16x8*)dst       = *(const f16x8*)&lt[r][q * 16];
  *(f16x8*)(dst + 8) = *(const f16x8*)&lt[r][q * 16 + 8];
}

// ---------------- GEMM1: h = silu(x@w1) * (x@w3), gathered rows ----------------
// 256 rows x (128 w1-cols + 128 w3-cols) per block. 8 waves 2Mx4N, BK=64,
// 4 phases/K-step, B frags preloaded to regs in phase 0, counted vmcnt(8).
// Grid.x padded 28->32 so dispatch-linear id % 8 == ct % 8: each XCD serves a
// fixed set of 3-4 ct columns -> B panels (~2 MB) stay L2-resident.
__global__ __launch_bounds__(512, 2) void gemm1_kernel(
    const _Float16* __restrict__ xh, const _Float16* __restrict__ w1t,
    const _Float16* __restrict__ w3t, const int* __restrict__ counts,
    const int* __restrict__ offsets, const int* __restrict__ tok_idx,
    const int* __restrict__ sched, _Float16* __restrict__ h) {
  int ct = blockIdx.x;
  if (ct >= FDIM / 128) return;  // padded dead columns (XCD affinity)
  int sc = sched[blockIdx.y];
  if (sc < 0) return;
  int e = sc >> 16, rt = sc & 0xFFFF;
  int cnt = counts[e];
  int off = offsets[e];

  // per buffer: A 256x64 (16384 f16) | B 256x64 (16384 f16)
  __shared__ _Float16 lds[2][32768];

  int tid = threadIdx.x, lane = tid & 63, wv = tid >> 6;
  int rsub = lane >> 3, p8 = lane & 7, cch = p8 ^ rsub;  // XOR-chunk swizzle (0 conflicts, measured)

  // A staging rows: wave wv covers quarter (wv>>1) of half (wv&1) -> consumed at phase wv>>1
  int R0 = (wv & 1) * 128 + (wv >> 1) * 32;
  const _Float16* aS[4];
#pragma unroll
  for (int g = 0; g < 4; g++) {
    int ir = rt * 256 + R0 + g * 8 + rsub;
    if (ir >= cnt) ir = cnt - 1;
    int tok = tok_idx[e * T_TOKENS + ir];
    aS[g] = xh + (size_t)tok * DDIM + cch * 8;
  }
  // B staging rows wv*32..+31: sel = wv&1, group = wv>>1 (constant per wave)
  const _Float16* wsel = (wv & 1) ? w3t : w1t;
  const _Float16* bS[4];
#pragma unroll
  for (int g = 0; g < 4; g++) {
    size_t row = (size_t)e * FDIM + (size_t)ct * 128 + (wv >> 1) * 32 + g * 8 + rsub;
    bS[g] = wsel + row * DDIM + cch * 8;
  }

  // prologue: stage K-tiles 0 and 1
  {
    _Float16* Lb = lds[0];
#pragma unroll
    for (int g = 0; g < 4; g++) gload16(aS[g], Lb + R0 * 64 + g * 512);
#pragma unroll
    for (int g = 0; g < 4; g++) gload16(bS[g], Lb + 16384 + wv * 2048 + g * 512);
  }
  {
    _Float16* Lb = lds[1];
#pragma unroll
    for (int g = 0; g < 4; g++) gload16(aS[g] + 64, Lb + R0 * 64 + g * 512);
#pragma unroll
    for (int g = 0; g < 4; g++) gload16(bS[g] + 64, Lb + 16384 + wv * 2048 + g * 512);
  }
#pragma unroll
  for (int g = 0; g < 4; g++) { aS[g] += 128; bS[g] += 128; }

  f32x4 acc[8][4];
  f32x4 zero = {0.f, 0.f, 0.f, 0.f};
#pragma unroll
  for (int m = 0; m < 8; m++)
#pragma unroll
    for (int j = 0; j < 4; j++) acc[m][j] = zero;

  int wm = (wv >> 2) * 128, wc = wv & 3;
  int l15 = lane & 15, qv = lane >> 4, x7 = l15 & 7;
  int pc0 = (qv ^ x7) * 8, pc1 = ((4 + qv) ^ x7) * 8;
  f16x8 bf[2][4];

  for (int t = 0; t < DDIM / 64; t++) {
    if (t < DDIM / 64 - 1) asm volatile("s_waitcnt vmcnt(8)" ::: "memory");
    else                   asm volatile("s_waitcnt vmcnt(0)" ::: "memory");
    BARRIER;  // buffer for tile t ready in all waves
    const _Float16* LA = lds[t & 1];
    const _Float16* LB = LA + 16384;
    _Float16* LbA = lds[t & 1] + R0 * 64;              // stage dest, tile t+2 (same parity)
    _Float16* LbB = lds[t & 1] + 16384 + wv * 2048;
    bool pf = (t < DDIM / 64 - 2);
    // phase 0: B preload (consumed entirely here) + A quad 0
    GPHASE(0,
      _Pragma("unroll")
      for (int j = 0; j < 4; j++) bf[0][j] = *(const f16x8*)&LB[(wc * 64 + j * 16 + l15) * 64 + pc0];
      _Pragma("unroll")
      for (int j = 0; j < 4; j++) bf[1][j] = *(const f16x8*)&LB[(wc * 64 + j * 16 + l15) * 64 + pc1];
    );
    // phase 1: stage B halves 0,1 (B region consumed at phase-0 closing barrier)
    GPHASE(1, if (pf) { gload16(bS[0], LbB); gload16(bS[1], LbB + 512); });
    // phase 2: stage B halves 2,3
    GPHASE(2, if (pf) { gload16(bS[2], LbB + 1024); gload16(bS[3], LbB + 1536); });
    // phase 3: waves with A-quarter <=2 (consumed by phase-2 close) stage A 0,1
    GPHASE(3, if (pf && wv < 6) { gload16(aS[0], LbA); gload16(aS[1], LbA + 512); });
    // tail: all A quarters consumed; finish A staging (8 issues/wave total)
    if (pf) {
      if (wv < 6) { gload16(aS[2], LbA + 1024); gload16(aS[3], LbA + 1536); }
      else {
        gload16(aS[0], LbA);        gload16(aS[1], LbA + 512);
        gload16(aS[2], LbA + 1024); gload16(aS[3], LbA + 1536);
      }
    }
#pragma unroll
    for (int g = 0; g < 4; g++) { aS[g] += 64; bS[g] += 64; }
  }

  int q4 = qv * 4;
#pragma unroll
  for (int m = 0; m < 8; m++) {
#pragma unroll
    for (int r = 0; r < 4; r++) {
      int row = rt * 256 + wm + m * 16 + q4 + r;
      if (row >= cnt) continue;
      _Float16* hrow = h + (size_t)(off + row) * FDIM + (size_t)ct * 128 + wc * 32;
#pragma unroll
      for (int j = 0; j < 2; j++) {
        float a = acc[m][j][r];      // w1 frag
        float b = acc[m][j + 2][r];  // matching w3 frag, same col
        float hv = (a / (1.f + __expf(-a))) * b;
        hrow[j * 16 + l15] = (_Float16)hv;
      }
    }
  }
}

// ---------------- GEMM2: part[slot] = w * (h[slot] @ w2[e]) -- no atomics ----------------
// 128 rows x 256 out-cols per block (halves h re-reads vs 128-col tiles).
// 8 waves 2Mx4N, wave out 64x64, acc[4][4], BK=64, 2 phases/K-step, B in regs.
// Grid (4, MAXT2): lin%8 = (4rt+ct)%8 -> each XCD serves exactly ONE ct
// (ct = xcd%4, rt parity split) -> its 1.75 MB w2t panel is L2-resident,
// perfectly balanced. 6 loads/wave/K-step -> vmcnt(6). LDS 96 KB.
__global__ __launch_bounds__(512, 2) void gemm2_kernel(
    const _Float16* __restrict__ h, const _Float16* __restrict__ w2t,
    const int* __restrict__ counts, const int* __restrict__ offsets,
    const float* __restrict__ tok_w, const int* __restrict__ sched,
    _Float16* __restrict__ part) {
  int sc = sched[blockIdx.y];
  if (sc < 0) return;
  int e = sc >> 16, rt = sc & 0xFFFF;
  int cnt = counts[e];
  int ct = blockIdx.x;  // 0..3
  int off = offsets[e];

  // per buffer: A 128x64 (8192 f16) | B 256x64 (16384 f16)
  __shared__ _Float16 lds[2][24576];

  int tid = threadIdx.x, lane = tid & 63, wv = tid >> 6;
  int rsub = lane >> 3, p8 = lane & 7, cch = p8 ^ rsub;

  // A: wave stages rows [wv*16, +16); consumed at phase (wv>>1)&1
  const _Float16* aS[2];
#pragma unroll
  for (int g = 0; g < 2; g++) {
    int ir = rt * 128 + wv * 16 + g * 8 + rsub;
    if (ir >= cnt) ir = cnt - 1;
    aS[g] = h + (size_t)(off + ir) * FDIM + cch * 8;
  }
  // B: wave stages w2t rows [ct*256 + wv*32, +32); consumed in phase 0 (preload)
  const _Float16* bS[4];
#pragma unroll
  for (int g = 0; g < 4; g++) {
    size_t row = (size_t)e * DDIM + (size_t)ct * 256 + wv * 32 + g * 8 + rsub;
    bS[g] = w2t + row * FDIM + cch * 8;
  }

  // prologue: stage K-tiles 0 and 1 (6 loads each)
  {
    _Float16* Lb = lds[0];
#pragma unroll
    for (int g = 0; g < 2; g++) gload16(aS[g], Lb + wv * 1024 + g * 512);
#pragma unroll
    for (int g = 0; g < 4; g++) gload16(bS[g], Lb + 8192 + wv * 2048 + g * 512);
  }
  {
    _Float16* Lb = lds[1];
#pragma unroll
    for (int g = 0; g < 2; g++) gload16(aS[g] + 64, Lb + wv * 1024 + g * 512);
#pragma unroll
    for (int g = 0; g < 4; g++) gload16(bS[g] + 64, Lb + 8192 + wv * 2048 + g * 512);
  }
#pragma unroll
  for (int g = 0; g < 2; g++) aS[g] += 128;
#pragma unroll
  for (int g = 0; g < 4; g++) bS[g] += 128;

  f32x4 acc[4][4];
  f32x4 zero = {0.f, 0.f, 0.f, 0.f};
#pragma unroll
  for (int m = 0; m < 4; m++)
#pragma unroll
    for (int j = 0; j < 4; j++) acc[m][j] = zero;

  int wm = (wv >> 2) * 64, wc = wv & 3;
  int l15 = lane & 15, qv = lane >> 4, x7 = l15 & 7;
  int pc0 = (qv ^ x7) * 8, pc1 = ((4 + qv) ^ x7) * 8;
  f16x8 bf[2][4];

  int aPh1 = (wv >> 1) & 1;  // my staged A rows are consumed in phase 1

  for (int t = 0; t < FDIM / 64; t++) {
    if (t < FDIM / 64 - 1) asm volatile("s_waitcnt vmcnt(6)" ::: "memory");
    else                   asm volatile("s_waitcnt vmcnt(0)" ::: "memory");
    BARRIER;
    const _Float16* LA = lds[t & 1];
    const _Float16* LB = LA + 8192;
    _Float16* LbA = lds[t & 1] + wv * 1024;
    _Float16* LbB = lds[t & 1] + 8192 + wv * 2048;
    bool pf = (t < FDIM / 64 - 2);
    // phase 0: B preload (fully consumed here) + A quad 0 (rows wm..wm+31)
    GPHASE(0,
      _Pragma("unroll")
      for (int j = 0; j < 4; j++) bf[0][j] = *(const f16x8*)&LB[(wc * 64 + j * 16 + l15) * 64 + pc0];
      _Pragma("unroll")
      for (int j = 0; j < 4; j++) bf[1][j] = *(const f16x8*)&LB[(wc * 64 + j * 16 + l15) * 64 + pc1];
    );
    // phase 1 window: B region free (phase-0 close); phase-0-consumed A rows free
    GPHASE(1, if (pf) {
      gload16(bS[0], LbB);        gload16(bS[1], LbB + 512);
      gload16(bS[2], LbB + 1024); gload16(bS[3], LbB + 1536);
      if (!aPh1) { gload16(aS[0], LbA); gload16(aS[1], LbA + 512); }
    });
    // tail: phase-1-consumed A rows free after phase-1 close
    if (pf && aPh1) { gload16(aS[0], LbA); gload16(aS[1], LbA + 512); }
#pragma unroll
    for (int g = 0; g < 2; g++) aS[g] += 64;
#pragma unroll
    for (int g = 0; g < 4; g++) bS[g] += 64;
  }

  int q4 = qv * 4;
#pragma unroll
  for (int m = 0; m < 4; m++) {
#pragma unroll
    for (int r = 0; r < 4; r++) {
      int row = rt * 128 + wm + m * 16 + q4 + r;
      if (row >= cnt) continue;
      float wgt = tok_w[e * T_TOKENS + row];
      _Float16* prow = part + (size_t)(off + row) * DDIM + (size_t)ct * 256 + wc * 64;
#pragma unroll
      for (int j = 0; j < 4; j++)
        prow[j * 16 + l15] = (_Float16)(acc[m][j][r] * wgt);
    }
  }
}

// ---------------- gather: out[t] = part[slotA(t)] + part[slotB(t)] ----------------
__global__ __launch_bounds__(256) void gather_kernel(
    const _Float16* __restrict__ part, const int2* __restrict__ tok_ref,
    const int* __restrict__ offsets, float* __restrict__ out) {
  int i = blockIdx.x * 256 + threadIdx.x;
  int t = i >> 7;            // 128 chunks of 8 per token
  int dc = (i & 127) * 8;
  int2 ref = tok_ref[t];
  int sa = offsets[ref.x >> 13] + (ref.x & 8191);
  int sb = offsets[ref.y >> 13] + (ref.y & 8191);
  f16x8 pa = *(const f16x8*)(part + (size_t)sa * DDIM + dc);
  f16x8 pb = *(const f16x8*)(part + (size_t)sb * DDIM + dc);
  float* dst = out + (size_t)t * DDIM + dc;
#pragma unroll
  for (int j = 0; j < 8; j++) dst[j] = (float)pa[j] + (float)pb[j];
}

// Workspace layout (MiB offsets; high-water ~= 338 MiB):
//   0: counts/offsets/sched1/sched2/tok_idx/tok_w/tok_ref (<1 MiB)
//   1: xh 16 | 17: w1t 56 | 73: w3t 56 | 129: w2t 56 | 185: h 119 | 304: part 33.6
extern "C" void kernel_launch(void* const* d_in, const int* in_sizes, int n_in,
                              void* d_out, int out_size, void* d_ws, size_t ws_size,
                              hipStream_t stream) {
  const float* x  = (const float*)d_in[0];
  const float* gw = (const float*)d_in[1];
  const float* w1 = (const float*)d_in[2];
  const float* w3 = (const float*)d_in[3];
  const float* w2 = (const float*)d_in[4];
  float* out = (float*)d_out;
  float* logits = out + (size_t)T_TOKENS * DDIM;

  char* ws = (char*)d_ws;
  const size_t MB = 1024 * 1024;
  int* counts  = (int*)ws;
  int* offsets = (int*)(ws + 64);
  int* sched1  = (int*)(ws + 128);               // 72 ints
  int* sched2  = (int*)(ws + 512);               // 136 ints
  int* tok_idx = (int*)(ws + 2048);              // 256 KB
  float* tok_w = (float*)(ws + 2048 + 262144);   // 256 KB
  int2* tok_ref = (int2*)(ws + 2048 + 2 * 262144);  // 64 KB
  _Float16* xh  = (_Float16*)(ws + 1 * MB);
  _Float16* w1t = (_Float16*)(ws + 17 * MB);
  _Float16* w3t = (_Float16*)(ws + 73 * MB);
  _Float16* w2t = (_Float16*)(ws + 129 * MB);
  _Float16* h   = (_Float16*)(ws + 185 * MB);
  _Float16* part = (_Float16*)(ws + 304 * MB);

  hipMemsetAsync(counts, 0, 256, stream);

  router_kernel<<<T_TOKENS / 4, 256, 0, stream>>>(x, gw, logits, counts, tok_idx, tok_w, tok_ref, xh);
  prefix_kernel<<<1, 64, 0, stream>>>(counts, offsets, sched1, sched2);

  transpose_f16_kernel<<<dim3(FDIM / 64, DDIM / 64, NEXP), 256, 0, stream>>>(w1, w1t, DDIM, FDIM);
  transpose_f16_kernel<<<dim3(FDIM / 64, DDIM / 64, NEXP), 256, 0, stream>>>(w3, w3t, DDIM, FDIM);
  transpose_f16_kernel<<<dim3(DDIM / 64, FDIM / 64, NEXP), 256, 0, stream>>>(w2, w2t, FDIM, DDIM);

  // grid.x padded to 32 so linear-id % 8 == ct % 8 (XCD affinity for B panels)
  gemm1_kernel<<<dim3(32, MAXT1), 512, 0, stream>>>(xh, w1t, w3t, counts, offsets, tok_idx, sched1, h);
  gemm2_kernel<<<dim3(DDIM / 256, MAXT2), 512, 0, stream>>>(h, w2t, counts, offsets, tok_w, sched2, part);
  gather_kernel<<<T_TOKENS * DDIM / 8 / 256, 256, 0, stream>>>(part, tok_ref, offsets, out);
}